// Round 4
// baseline (17730.511 us; speedup 1.0000x reference)
//
#include <hip/hip_runtime.h>
#include <cmath>

#define B_   64
#define T_   512
#define IN_  256
#define H_   512
#define OUT_ 256
#define M_   (B_*T_)
#define RP   16      // recurrence participants (blocks, all on ONE XCD)

typedef __bf16 bf16x4 __attribute__((ext_vector_type(4)));
typedef __bf16 bf16x8 __attribute__((ext_vector_type(8)));
typedef float  f32x4  __attribute__((ext_vector_type(4)));

static __device__ __forceinline__ void split_f32(float x, __bf16 &hi, __bf16 &lo) {
    unsigned u  = __float_as_uint(x);
    unsigned hu = u & 0xffff0000u;
    hi = __builtin_bit_cast(__bf16, (unsigned short)(hu >> 16));
    lo = (__bf16)(x - __uint_as_float(hu));
}

// ---------------- weight prep ----------------
__global__ void split_arr(const float* __restrict__ src, __bf16* __restrict__ hi,
                          __bf16* __restrict__ lo, int n) {
    int i = blockIdx.x * 256 + threadIdx.x;
    if (i < n) { __bf16 h, l; split_f32(src[i], h, l); hi[i] = h; lo[i] = l; }
}

__global__ void bias_comb(const float* __restrict__ a, const float* __restrict__ b,
                          float* __restrict__ o, int n) {
    int i = blockIdx.x * 256 + threadIdx.x;
    if (i < n) o[i] = a[i] + b[i];
}

// ---------------- xp GEMM (fp32 A): C[M,512] = A @ W^T + bias ----------------
#define GBM 128
#define GBN 64
#define GBK 32
#define LDA 40

__global__ __launch_bounds__(256) void gemm_xp(
    const float* __restrict__ A, const __bf16* __restrict__ Whi,
    const __bf16* __restrict__ Wlo, const float* __restrict__ bias,
    float* __restrict__ C, int K)
{
    __shared__ __bf16 sAhi[GBM*LDA], sAlo[GBM*LDA], sBhi[GBN*LDA], sBlo[GBN*LDA];
    const int tid = threadIdx.x;
    const int m0 = blockIdx.y * GBM, n0 = blockIdx.x * GBN;
    const int wave = tid >> 6, lane = tid & 63, lm = lane & 15, q = lane >> 4;

    f32x4 acc[2][4];
#pragma unroll
    for (int i = 0; i < 2; ++i)
#pragma unroll
        for (int j = 0; j < 4; ++j) acc[i][j] = (f32x4){0.f,0.f,0.f,0.f};

    for (int k0 = 0; k0 < K; k0 += GBK) {
        __syncthreads();
#pragma unroll
        for (int i = 0; i < 4; ++i) {
            int c = tid + i * 256;
            int row = c >> 3, pos = c & 7;
            float4 v = *(const float4*)(&A[(size_t)(m0+row)*K + k0 + pos*4]);
            __bf16 h0,l0,h1,l1,h2,l2,h3,l3;
            split_f32(v.x,h0,l0); split_f32(v.y,h1,l1);
            split_f32(v.z,h2,l2); split_f32(v.w,h3,l3);
            *(bf16x4*)(&sAhi[row*LDA + pos*4]) = (bf16x4){h0,h1,h2,h3};
            *(bf16x4*)(&sAlo[row*LDA + pos*4]) = (bf16x4){l0,l1,l2,l3};
        }
        {
            int row = tid >> 2, pos = (tid & 3) * 8;
            *(bf16x8*)(&sBhi[row*LDA + pos]) =
                *(const bf16x8*)(&Whi[(size_t)(n0+row)*K + k0 + pos]);
            *(bf16x8*)(&sBlo[row*LDA + pos]) =
                *(const bf16x8*)(&Wlo[(size_t)(n0+row)*K + k0 + pos]);
        }
        __syncthreads();

        bf16x8 ah[2], al[2], bh[4], bl[4];
#pragma unroll
        for (int mt = 0; mt < 2; ++mt) {
            int r = wave*32 + mt*16 + lm;
            ah[mt] = *(const bf16x8*)(&sAhi[r*LDA + q*8]);
            al[mt] = *(const bf16x8*)(&sAlo[r*LDA + q*8]);
        }
#pragma unroll
        for (int nt = 0; nt < 4; ++nt) {
            int r = nt*16 + lm;
            bh[nt] = *(const bf16x8*)(&sBhi[r*LDA + q*8]);
            bl[nt] = *(const bf16x8*)(&sBlo[r*LDA + q*8]);
        }
#pragma unroll
        for (int mt = 0; mt < 2; ++mt)
#pragma unroll
            for (int nt = 0; nt < 4; ++nt) {
                acc[mt][nt] = __builtin_amdgcn_mfma_f32_16x16x32_bf16(ah[mt], bh[nt], acc[mt][nt], 0,0,0);
                acc[mt][nt] = __builtin_amdgcn_mfma_f32_16x16x32_bf16(ah[mt], bl[nt], acc[mt][nt], 0,0,0);
                acc[mt][nt] = __builtin_amdgcn_mfma_f32_16x16x32_bf16(al[mt], bh[nt], acc[mt][nt], 0,0,0);
            }
    }
#pragma unroll
    for (int mt = 0; mt < 2; ++mt)
#pragma unroll
        for (int nt = 0; nt < 4; ++nt)
#pragma unroll
            for (int r = 0; r < 4; ++r) {
                int m = m0 + wave*32 + mt*16 + q*4 + r;
                int n = n0 + nt*16 + lm;
                C[(size_t)m*H_ + n] = acc[mt][nt][r] + bias[n];
            }
}

// ---------------- xp GEMM (packed hi|lo A from layer-0 output) ----------------
__global__ __launch_bounds__(256) void gemm_xp_pk(
    const uint32_t* __restrict__ Ap, const __bf16* __restrict__ Whi,
    const __bf16* __restrict__ Wlo, const float* __restrict__ bias,
    float* __restrict__ C, int K)
{
    __shared__ __bf16 sAhi[GBM*LDA], sAlo[GBM*LDA], sBhi[GBN*LDA], sBlo[GBN*LDA];
    const int tid = threadIdx.x;
    const int m0 = blockIdx.y * GBM, n0 = blockIdx.x * GBN;
    const int wave = tid >> 6, lane = tid & 63, lm = lane & 15, q = lane >> 4;

    f32x4 acc[2][4];
#pragma unroll
    for (int i = 0; i < 2; ++i)
#pragma unroll
        for (int j = 0; j < 4; ++j) acc[i][j] = (f32x4){0.f,0.f,0.f,0.f};

    for (int k0 = 0; k0 < K; k0 += GBK) {
        __syncthreads();
#pragma unroll
        for (int i = 0; i < 4; ++i) {
            int c = tid + i * 256;
            int row = c >> 3, pos = c & 7;
            uint4 dv = *(const uint4*)(&Ap[(size_t)(m0+row)*K + k0 + pos*4]);
            uint32_t h01 = __builtin_amdgcn_perm(dv.y, dv.x, 0x07060302);
            uint32_t h23 = __builtin_amdgcn_perm(dv.w, dv.z, 0x07060302);
            uint32_t l01 = __builtin_amdgcn_perm(dv.y, dv.x, 0x05040100);
            uint32_t l23 = __builtin_amdgcn_perm(dv.w, dv.z, 0x05040100);
            *(uint2*)(&sAhi[row*LDA + pos*4]) = make_uint2(h01, h23);
            *(uint2*)(&sAlo[row*LDA + pos*4]) = make_uint2(l01, l23);
        }
        {
            int row = tid >> 2, pos = (tid & 3) * 8;
            *(bf16x8*)(&sBhi[row*LDA + pos]) =
                *(const bf16x8*)(&Whi[(size_t)(n0+row)*K + k0 + pos]);
            *(bf16x8*)(&sBlo[row*LDA + pos]) =
                *(const bf16x8*)(&Wlo[(size_t)(n0+row)*K + k0 + pos]);
        }
        __syncthreads();

        bf16x8 ah[2], al[2], bh[4], bl[4];
#pragma unroll
        for (int mt = 0; mt < 2; ++mt) {
            int r = wave*32 + mt*16 + lm;
            ah[mt] = *(const bf16x8*)(&sAhi[r*LDA + q*8]);
            al[mt] = *(const bf16x8*)(&sAlo[r*LDA + q*8]);
        }
#pragma unroll
        for (int nt = 0; nt < 4; ++nt) {
            int r = nt*16 + lm;
            bh[nt] = *(const bf16x8*)(&sBhi[r*LDA + q*8]);
            bl[nt] = *(const bf16x8*)(&sBlo[r*LDA + q*8]);
        }
#pragma unroll
        for (int mt = 0; mt < 2; ++mt)
#pragma unroll
            for (int nt = 0; nt < 4; ++nt) {
                acc[mt][nt] = __builtin_amdgcn_mfma_f32_16x16x32_bf16(ah[mt], bh[nt], acc[mt][nt], 0,0,0);
                acc[mt][nt] = __builtin_amdgcn_mfma_f32_16x16x32_bf16(ah[mt], bl[nt], acc[mt][nt], 0,0,0);
                acc[mt][nt] = __builtin_amdgcn_mfma_f32_16x16x32_bf16(al[mt], bh[nt], acc[mt][nt], 0,0,0);
            }
    }
#pragma unroll
    for (int mt = 0; mt < 2; ++mt)
#pragma unroll
        for (int nt = 0; nt < 4; ++nt)
#pragma unroll
            for (int r = 0; r < 4; ++r) {
                int m = m0 + wave*32 + mt*16 + q*4 + r;
                int n = n0 + nt*16 + lm;
                C[(size_t)m*H_ + n] = acc[mt][nt][r] + bias[n];
            }
}

// ---------------- recurrence: 16 blocks pinned to ONE XCD, L2-local exchange ----------------
// Launch 128 blocks; each reads its physical XCD (HW_REG_XCC_ID) and registers
// via device-scope atomicAdd. First XCD to collect RP=16 blocks wins (CAS);
// everyone else exits. 84 KB dynamic LDS forces 1 block/CU, so the winners
// occupy 16 distinct CUs sharing one L2. Per step: plain h stores stay DIRTY
// in the shared L2 (dirty lines survive buffer_inv — proven in r3 by out0p);
// per-block monotonic flag words (plain stores) form the barrier; consumers
// poll flags with buffer_inv sc1 + plain loads (L1 flush, L2 hit). Zero
// fabric traffic per step.
__global__ __launch_bounds__(512) void rnn_rec_x(
    const float* __restrict__ xp,                        // [B,T,H] fp32
    const __bf16* __restrict__ Whi, const __bf16* __restrict__ Wlo,  // [H,H]
    uint32_t* __restrict__ hbuf,                         // [2][B*H] packed hi|lo, zeroed
    uint32_t* __restrict__ outp,                         // [B,T,H] packed or null
    float* __restrict__ olast,                           // [B,H] or null
    int* __restrict__ ctrl)                              // [0..15] cnt, [16] winner, [32..47] flags; zeroed
{
    extern __shared__ __bf16 smem[];
    __bf16* sWhi = smem;             // 32 cols x 512, XOR-swizzled
    __bf16* sWlo = smem + 32*512;

    __shared__ int s_rank;
    const int tid = threadIdx.x;

    if (tid == 0) {
        unsigned xcd;
        asm volatile("s_getreg_b32 %0, hwreg(HW_REG_XCC_ID)" : "=s"(xcd));
        xcd &= 15u;
        int slot = atomicAdd(&ctrl[xcd], 1);             // device scope
        int rank = -1;
        if (slot < RP) {
            if (slot == RP - 1) atomicCAS(&ctrl[16], 0, (int)xcd + 1);
            int wv;
            while ((wv = __hip_atomic_load(&ctrl[16], __ATOMIC_RELAXED,
                                           __HIP_MEMORY_SCOPE_AGENT)) == 0)
                __builtin_amdgcn_s_sleep(8);
            if (wv == (int)xcd + 1) rank = slot;
        }
        s_rank = rank;
    }
    __syncthreads();
    const int rank = s_rank;
    if (rank < 0) return;

    volatile int* flags = ctrl + 32;
    const int n0 = rank * 32;

    // stage W slice (32x512 hi+lo) with XOR swizzle (verified in r3)
#pragma unroll
    for (int i = 0; i < 4; ++i) {
        int cl = tid + i*512;                 // 0..2047
        int j = cl >> 6, c = cl & 63;
        int dst = (j*64 + (c ^ (j & 7))) * 8;
        *(bf16x8*)(&sWhi[dst]) = *(const bf16x8*)(&Whi[(size_t)(n0+j)*H_ + c*8]);
        *(bf16x8*)(&sWlo[dst]) = *(const bf16x8*)(&Wlo[(size_t)(n0+j)*H_ + c*8]);
    }
    __syncthreads();

    const int wave = tid >> 6, lane = tid & 63, lm = lane & 15, q = lane >> 4;
    const int mt = wave & 3, nt = wave >> 2;  // 4 batch-tiles x 2 col-tiles
    const int mr0 = mt * 16;                  // batch rows of this wave's tile
    const int jn  = nt*16 + lm;               // local col 0..31
    const int n   = n0 + jn;                  // global col
    const int swz = jn & 7;

    for (int t = 0; t < T_; ++t) {
        const uint32_t* hc = hbuf + (size_t)(t & 1) * (B_*H_);
        uint32_t*       hn = hbuf + (size_t)((t+1) & 1) * (B_*H_);

        // xp for this step's outputs (overlaps the MFMA chain)
        float xv[4];
#pragma unroll
        for (int r = 0; r < 4; ++r)
            xv[r] = xp[((size_t)(mr0 + q*4 + r)*T_ + t)*H_ + n];

        // two independent accumulator chains (even/odd kt) -> 4 chains/SIMD
        f32x4 acc0 = (f32x4){0.f,0.f,0.f,0.f};
        f32x4 acc1 = (f32x4){0.f,0.f,0.f,0.f};
#pragma unroll
        for (int kp = 0; kp < 8; ++kp) {
#pragma unroll
            for (int s = 0; s < 2; ++s) {
                const int kt = kp*2 + s;
                const uint32_t* ap = &hc[(size_t)(mr0+lm)*H_ + kt*32 + q*8];
                uint4 d0 = *(const uint4*)ap;
                uint4 d1 = *(const uint4*)(ap + 4);
                uint32_t h0 = __builtin_amdgcn_perm(d0.y, d0.x, 0x07060302);
                uint32_t h1 = __builtin_amdgcn_perm(d0.w, d0.z, 0x07060302);
                uint32_t h2 = __builtin_amdgcn_perm(d1.y, d1.x, 0x07060302);
                uint32_t h3 = __builtin_amdgcn_perm(d1.w, d1.z, 0x07060302);
                uint32_t l0 = __builtin_amdgcn_perm(d0.y, d0.x, 0x05040100);
                uint32_t l1 = __builtin_amdgcn_perm(d0.w, d0.z, 0x05040100);
                uint32_t l2 = __builtin_amdgcn_perm(d1.y, d1.x, 0x05040100);
                uint32_t l3 = __builtin_amdgcn_perm(d1.w, d1.z, 0x05040100);
                bf16x8 ah = __builtin_bit_cast(bf16x8, make_uint4(h0,h1,h2,h3));
                bf16x8 al = __builtin_bit_cast(bf16x8, make_uint4(l0,l1,l2,l3));
                const int woff = (jn*64 + (((kt*4) + q) ^ swz)) * 8;
                bf16x8 bh = *(const bf16x8*)(&sWhi[woff]);
                bf16x8 bl = *(const bf16x8*)(&sWlo[woff]);
                if (s == 0) {
                    acc0 = __builtin_amdgcn_mfma_f32_16x16x32_bf16(ah, bh, acc0, 0,0,0);
                    acc0 = __builtin_amdgcn_mfma_f32_16x16x32_bf16(ah, bl, acc0, 0,0,0);
                    acc0 = __builtin_amdgcn_mfma_f32_16x16x32_bf16(al, bh, acc0, 0,0,0);
                } else {
                    acc1 = __builtin_amdgcn_mfma_f32_16x16x32_bf16(ah, bh, acc1, 0,0,0);
                    acc1 = __builtin_amdgcn_mfma_f32_16x16x32_bf16(ah, bl, acc1, 0,0,0);
                    acc1 = __builtin_amdgcn_mfma_f32_16x16x32_bf16(al, bh, acc1, 0,0,0);
                }
            }
        }

#pragma unroll
        for (int r = 0; r < 4; ++r) {
            const int b = mr0 + q*4 + r;
            float v = xv[r] + acc0[r] + acc1[r];
            float e  = __expf(2.f*v);
            float hv = 1.f - 2.f/(e + 1.f);
            unsigned u  = __float_as_uint(hv);
            unsigned hu = u & 0xffff0000u;
            __bf16 hlb = (__bf16)(hv - __uint_as_float(hu));
            uint32_t pk = hu | (uint32_t)__builtin_bit_cast(unsigned short, hlb);
            hn[(size_t)b*H_ + n] = pk;
            if (outp) outp[((size_t)b*T_ + t)*H_ + n] = pk;
            if (olast && t == T_-1) olast[(size_t)b*H_ + n] = hv;
        }

        if (t < T_-1) {
            asm volatile("s_waitcnt vmcnt(0)" ::: "memory");  // h stores in L2
            __syncthreads();
            if (tid == 0) {
                flags[rank] = t + 1;                          // plain dirty-L2 store
                asm volatile("s_waitcnt vmcnt(0)" ::: "memory");
                for (;;) {
                    asm volatile("buffer_inv sc1" ::: "memory");
                    bool ok = true;
#pragma unroll
                    for (int i = 0; i < RP; ++i) ok &= (flags[i] >= t + 1);
                    if (ok) break;
                    __builtin_amdgcn_s_sleep(1);
                }
            }
            __syncthreads();
            asm volatile("buffer_inv sc1" ::: "memory");      // L1 fresh for h reads
        }
    }
}

// ---------------- output projection ----------------
__global__ __launch_bounds__(256) void out_proj(
    const float* __restrict__ hlast, const float* __restrict__ Wout,
    const float* __restrict__ bout, float* __restrict__ out)
{
    __shared__ float sh[H_];
    int b = blockIdx.x;
    for (int i = threadIdx.x; i < H_; i += 256) sh[i] = hlast[(size_t)b*H_ + i];
    __syncthreads();
    int o = threadIdx.x;
    const float* wr = &Wout[(size_t)o*H_];
    float acc = 0.f;
#pragma unroll 4
    for (int k = 0; k < H_; k += 4) {
        float4 wv = *(const float4*)(&wr[k]);
        acc += wv.x*sh[k] + wv.y*sh[k+1] + wv.z*sh[k+2] + wv.w*sh[k+3];
    }
    out[(size_t)b*OUT_ + o] = bout[o] + acc;
}

extern "C" void kernel_launch(void* const* d_in, const int* in_sizes, int n_in,
                              void* d_out, int out_size, void* d_ws, size_t ws_size,
                              hipStream_t stream)
{
    const float* x    = (const float*)d_in[0];
    const float* Wih0 = (const float*)d_in[1];
    const float* Whh0 = (const float*)d_in[2];
    const float* bih0 = (const float*)d_in[3];
    const float* bhh0 = (const float*)d_in[4];
    const float* Wih1 = (const float*)d_in[5];
    const float* Whh1 = (const float*)d_in[6];
    const float* bih1 = (const float*)d_in[7];
    const float* bhh1 = (const float*)d_in[8];
    const float* Wout = (const float*)d_in[9];
    const float* bout = (const float*)d_in[10];

    char* w = (char*)d_ws;
    size_t off = 0;
    auto alloc = [&](size_t bytes) -> void* {
        void* p = w + off; off = (off + bytes + 255) & ~(size_t)255; return p;
    };
    float*    xp     = (float*)   alloc((size_t)M_*H_*4);   // 64 MB
    uint32_t* out0p  = (uint32_t*)alloc((size_t)M_*H_*4);   // 64 MB packed hi|lo
    __bf16* wih0hi = (__bf16*)alloc((size_t)H_*IN_*2);
    __bf16* wih0lo = (__bf16*)alloc((size_t)H_*IN_*2);
    __bf16* whh0hi = (__bf16*)alloc((size_t)H_*H_*2);
    __bf16* whh0lo = (__bf16*)alloc((size_t)H_*H_*2);
    __bf16* wih1hi = (__bf16*)alloc((size_t)H_*H_*2);
    __bf16* wih1lo = (__bf16*)alloc((size_t)H_*H_*2);
    __bf16* whh1hi = (__bf16*)alloc((size_t)H_*H_*2);
    __bf16* whh1lo = (__bf16*)alloc((size_t)H_*H_*2);
    float*  bias0  = (float*) alloc(H_*4);
    float*  bias1  = (float*) alloc(H_*4);
    float*  hlast  = (float*) alloc((size_t)B_*H_*4);
    size_t zstart = off;                                    // zero region
    uint32_t* hbuf0 = (uint32_t*)alloc((size_t)2*B_*H_*4);  // 256 KB
    uint32_t* hbuf1 = (uint32_t*)alloc((size_t)2*B_*H_*4);  // 256 KB
    int*      ctrl0 = (int*)     alloc(256);
    int*      ctrl1 = (int*)     alloc(256);
    size_t zlen = off - zstart;

    hipMemsetAsync(w + zstart, 0, zlen, stream);

    split_arr<<<(H_*IN_+255)/256, 256, 0, stream>>>(Wih0, wih0hi, wih0lo, H_*IN_);
    split_arr<<<(H_*H_ +255)/256, 256, 0, stream>>>(Whh0, whh0hi, whh0lo, H_*H_);
    split_arr<<<(H_*H_ +255)/256, 256, 0, stream>>>(Wih1, wih1hi, wih1lo, H_*H_);
    split_arr<<<(H_*H_ +255)/256, 256, 0, stream>>>(Whh1, whh1hi, whh1lo, H_*H_);
    bias_comb<<<2, 256, 0, stream>>>(bih0, bhh0, bias0, H_);
    bias_comb<<<2, 256, 0, stream>>>(bih1, bhh1, bias1, H_);

    // 84 KB dynamic LDS: forces 1 block/CU so the 16 winners sit on 16 CUs
    const int DYN_LDS = 86016;
    hipFuncSetAttribute(reinterpret_cast<const void*>(rnn_rec_x),
                        hipFuncAttributeMaxDynamicSharedMemorySize, DYN_LDS);

    dim3 ggrid(H_/GBN, M_/GBM);  // (8, 256)
    gemm_xp<<<ggrid, 256, 0, stream>>>(x, wih0hi, wih0lo, bias0, xp, IN_);
    rnn_rec_x<<<128, 512, DYN_LDS, stream>>>(xp, whh0hi, whh0lo, hbuf0, out0p, nullptr, ctrl0);
    gemm_xp_pk<<<ggrid, 256, 0, stream>>>(out0p, wih1hi, wih1lo, bias1, xp, H_);
    rnn_rec_x<<<128, 512, DYN_LDS, stream>>>(xp, whh1hi, whh1lo, hbuf1, nullptr, hlast, ctrl1);
    out_proj<<<B_, 256, 0, stream>>>(hlast, Wout, bout, (float*)d_out);
}